// Round 8
// baseline (334.585 us; speedup 1.0000x reference)
//
#include <hip/hip_runtime.h>

// Problem constants (from reference setup_inputs)
#define BB 4
#define CC 64
#define HH 56
#define WW 56
#define HW (HH*WW)

typedef unsigned short u16;
typedef __attribute__((ext_vector_type(8))) short bf16x8;
typedef __attribute__((ext_vector_type(4))) float f32x4;

__device__ __forceinline__ u16 f2bf(float f) {
    union { float f; unsigned u; } c; c.f = f;
    unsigned u = c.u;
    u = (u + 0x7FFFu + ((u >> 16) & 1u)) >> 16;   // RNE
    return (u16)u;
}
__device__ __forceinline__ float bf2f(u16 v) {
    union { unsigned u; float f; } c; c.u = ((unsigned)v) << 16;
    return c.f;
}

// ---------------------------------------------------------------------------
// Fused prep: all weight reshape/cast in ONE launch.
// ---------------------------------------------------------------------------
#define R1 102400
#define R2 351232
#define R3 4096
#define R4 1600
#define R5 3136
__global__ __launch_bounds__(256)
void prep_all_kernel(const float* __restrict__ ow1, const float* __restrict__ ow2,
                     const float* __restrict__ pw,  const float* __restrict__ dw1,
                     const float* __restrict__ dw2,
                     u16* __restrict__ w2t1, u16* __restrict__ w2t2,
                     u16* __restrict__ pwT, float* __restrict__ dwT1,
                     float* __restrict__ dwT2) {
    const int i = blockIdx.x*256 + threadIdx.x;
    if (i < R1) {
        const int ic = i & 63, n = (i >> 6) & 63, tap = i >> 12;
        w2t1[i] = f2bf((n < 50) ? ow1[((size_t)n*64 + ic)*25 + tap] : 0.f);
    } else if (i < R1+R2) {
        const int j = i - R1;
        const int ic = j & 63, n = (j >> 6) % 112, tap = j / 7168;
        w2t2[j] = f2bf((n < 98) ? ow2[((size_t)n*64 + ic)*49 + tap] : 0.f);
    } else if (i < R1+R2+R3) {
        const int j = i - (R1+R2);
        pwT[j] = f2bf(pw[j]);
    } else if (i < R1+R2+R3+R4) {
        const int j = i - (R1+R2+R3);
        const int c = j & 63, k = j >> 6;
        dwT1[j] = dw1[c*25 + k];
    } else if (i < R1+R2+R3+R4+R5) {
        const int j = i - (R1+R2+R3+R4);
        const int c = j & 63, k = j >> 6;
        dwT2[j] = dw2[c*49 + k];
    }
}

// ---------------------------------------------------------------------------
// Transpose + cast: in (B,CC,HW) fp32 -> out (B,HW,CC) bf16.
// ---------------------------------------------------------------------------
__global__ __launch_bounds__(256)
void transpose_bf16_kernel(const float* __restrict__ in, u16* __restrict__ out) {
    __shared__ u16 tile[64][72];
    const int blk = blockIdx.x;
    const int b   = blk / (HW/64);
    const int p0  = (blk % (HW/64))*64;
    const int t   = threadIdx.x;

    const int px  = t & 63, icq = t >> 6;
    const float* ip = in + ((size_t)b*CC + icq*16)*HW + p0 + px;
    #pragma unroll
    for (int i = 0; i < 16; ++i)
        tile[px][icq*16 + i] = f2bf(ip[(size_t)i*HW]);
    __syncthreads();

    const int px2 = t >> 2, g = t & 3;
    u16* op = out + ((size_t)b*HW + p0 + px2)*64 + g*16;
    const uint4* s = (const uint4*)&tile[px2][g*16];
    ((uint4*)op)[0] = s[0];
    ((uint4*)op)[1] = s[1];
}

// ---------------------------------------------------------------------------
// Barrier-free MFMA implicit-GEMM conv, occupancy-tuned: wave = 16 pixels x
// ONE 16-wide n-tile (blockIdx.y). Grid conv2: 196x7 = 1372 blocks = 5488
// waves (vs 1568 in round 7). Tap loop unrolled 4x -> ~16 b128 loads in
// flight per wave. No LDS, no __syncthreads.
// A: lane = A[m=lane&15][k=quad*8+j]; B: lane = B[k=quad*8+j][n=lane&15];
// C: n=lane&15, m=quad*4+reg.
// ---------------------------------------------------------------------------
template<int K, int DIL, int PAD, int COUT, int NP>
__global__ __launch_bounds__(256)
void conv_mfma_kernel(const u16* __restrict__ xT, const u16* __restrict__ w2t,
                      const float* __restrict__ bias, float* __restrict__ out) {
    constexpr int KK = K*K;
    const int nm   = HW/64;
    const int b    = blockIdx.x / nm;
    const int p0   = (blockIdx.x % nm)*64 + (threadIdx.x >> 6)*16;
    const int nt0  = blockIdx.y;
    const int lane = threadIdx.x & 63;
    const int r    = lane & 15;
    const int quad = lane >> 4;
    const int p    = p0 + r;
    const int py   = p / WW;
    const int pxx  = p % WW;
    const u16* abase = xT + (size_t)b*HW*64 + (size_t)quad*8;
    const u16* bbase = w2t + ((size_t)nt0*16 + r)*64 + quad*8;
    const bf16x8 zero8 = (bf16x8)0;

    f32x4 acc = (f32x4){0.f,0.f,0.f,0.f};

    #pragma unroll 4
    for (int tap = 0; tap < KK; ++tap) {
        const int dyy = (tap/K)*DIL - PAD;
        const int dxx = (tap%K)*DIL - PAD;
        const int yy  = py + dyy, xx2 = pxx + dxx;
        const bool valid = ((unsigned)yy < (unsigned)HH) && ((unsigned)xx2 < (unsigned)WW);
        const int sp = valid ? (p + dyy*WW + dxx) : 0;

        const u16* ap = abase + (size_t)sp*64;
        bf16x8 av0 = *(const bf16x8*)(ap);
        bf16x8 av1 = *(const bf16x8*)(ap + 32);
        if (!valid) { av0 = zero8; av1 = zero8; }

        const u16* bp = bbase + (size_t)tap*NP*64;
        const bf16x8 bv0 = *(const bf16x8*)(bp);
        const bf16x8 bv1 = *(const bf16x8*)(bp + 32);
        acc = __builtin_amdgcn_mfma_f32_16x16x32_bf16(av0, bv0, acc, 0, 0, 0);
        acc = __builtin_amdgcn_mfma_f32_16x16x32_bf16(av1, bv1, acc, 0, 0, 0);
    }

    const int n = nt0*16 + r;
    if (n < COUT) {
        const float bv = bias[n];
        float* op = out + ((size_t)b*COUT + n)*HW + p0 + quad*4;
        #pragma unroll
        for (int r2 = 0; r2 < 4; ++r2) op[r2] = acc[r2] + bv;
    }
}

// ---------------------------------------------------------------------------
// Channel-last deformable bilinear + depthwise. Wave = one pixel, lane =
// channel. gw forced wave-uniform via readfirstlane so offset loads and
// coordinate math scalarize (s_load, frees VMEM slots).
// ---------------------------------------------------------------------------
template<int K, int DIL, int PAD>
__global__ __launch_bounds__(256)
void deform_cl_kernel(const u16* __restrict__ inT, const float* __restrict__ off,
                      const float* __restrict__ dwT, u16* __restrict__ outT) {
    constexpr int KK = K*K;
    const int gw   = __builtin_amdgcn_readfirstlane((blockIdx.x*256 + threadIdx.x) >> 6);
    const int lane = threadIdx.x & 63;
    const int p = gw % HW;
    const int b = gw / HW;
    const int h = p / WW, w = p % WW;

    const u16*   ib   = inT + (size_t)b*HW*64 + lane;
    const float* offp = off + (size_t)b*(2*KK)*HW + p;

    float acc = 0.f;
    #pragma unroll 7
    for (int k = 0; k < KK; ++k) {
        const float dy = offp[(size_t)(2*k  )*HW];
        const float dx = offp[(size_t)(2*k+1)*HW];
        const float py = (float)(h + (k/K)*DIL - PAD) + dy;
        const float px = (float)(w + (k%K)*DIL - PAD) + dx;
        const float y0f = floorf(py), x0f = floorf(px);
        const float wy1 = py - y0f,  wx1 = px - x0f;
        const float wy0 = 1.f - wy1, wx0 = 1.f - wx1;
        const int y0 = (int)y0f, x0 = (int)x0f;

        const int y0c = min(max(y0,   0), HH-1);
        const int y1c = min(max(y0+1, 0), HH-1);
        const int x0c = min(max(x0,   0), WW-1);
        const int x1c = min(max(x0+1, 0), WW-1);
        const float gy0 = wy0 * ((y0   >= 0 && y0   < HH) ? 1.f : 0.f);
        const float gy1 = wy1 * ((y0+1 >= 0 && y0+1 < HH) ? 1.f : 0.f);
        const float gx0 = wx0 * ((x0   >= 0 && x0   < WW) ? 1.f : 0.f);
        const float gx1 = wx1 * ((x0+1 >= 0 && x0+1 < WW) ? 1.f : 0.f);

        const int r0 = y0c*WW, r1 = y1c*WW;
        const float v00 = bf2f(ib[(size_t)(r0 + x0c)*64]);
        const float v01 = bf2f(ib[(size_t)(r0 + x1c)*64]);
        const float v10 = bf2f(ib[(size_t)(r1 + x0c)*64]);
        const float v11 = bf2f(ib[(size_t)(r1 + x1c)*64]);

        const float s = (v00*gx0 + v01*gx1)*gy0 + (v10*gx0 + v11*gx1)*gy1;
        acc += s * dwT[k*CC + lane];
    }
    outT[(size_t)gw*64 + lane] = f2bf(acc);
}

// ---------------------------------------------------------------------------
// Pointwise 1x1 via MFMA + fused residual multiply; wave = 16 px x 1 n-tile.
// ---------------------------------------------------------------------------
__global__ __launch_bounds__(256)
void pw_mfma_kernel(const u16* __restrict__ a2T, const u16* __restrict__ pwT,
                    const float* __restrict__ pb, const float* __restrict__ x,
                    float* __restrict__ out) {
    const int nm = HW/64;
    const int b  = blockIdx.x / nm;
    const int p0 = (blockIdx.x % nm)*64 + (threadIdx.x >> 6)*16;
    const int nt = blockIdx.y;
    const int lane = threadIdx.x & 63;
    const int r = lane & 15, quad = lane >> 4;

    const u16* ap = a2T + ((size_t)b*HW + p0 + r)*64 + quad*8;
    f32x4 acc = (f32x4){0.f,0.f,0.f,0.f};
    #pragma unroll
    for (int ks = 0; ks < 2; ++ks) {
        const bf16x8 av = *(const bf16x8*)(ap + ks*32);
        const bf16x8 bv = *(const bf16x8*)(pwT + ((size_t)(nt*16 + r))*64 + ks*32 + quad*8);
        acc = __builtin_amdgcn_mfma_f32_16x16x32_bf16(av, bv, acc, 0, 0, 0);
    }

    const int n = nt*16 + r;
    const float bv = pb[n];
    const size_t base = ((size_t)b*CC + n)*HW + p0 + quad*4;
    #pragma unroll
    for (int r2 = 0; r2 < 4; ++r2)
        out[base + r2] = x[base + r2] * (acc[r2] + bv);
}

// ======================= fallback fp32 kernels (low ws) =====================
template<int K, int DIL, int PAD, int COUT, int OCB>
__global__ __launch_bounds__(256)
void off_conv_sg_kernel(const float* __restrict__ in, const float* __restrict__ wgt,
                        const float* __restrict__ bias, float* __restrict__ out) {
    constexpr int KK = K*K;
    const int nOB = COUT / OCB;
    const int b   = blockIdx.x / nOB;
    const int oc0 = (blockIdx.x % nOB) * OCB;
    const int x   = threadIdx.x;
    const int h   = blockIdx.y*4 + threadIdx.y;

    float acc[OCB];
    #pragma unroll
    for (int o = 0; o < OCB; ++o) acc[o] = bias[oc0+o];

    const float* inb = in + (size_t)b*CC*HW;
    const float* wb  = wgt + (size_t)oc0*CC*KK;

    for (int ic = 0; ic < CC; ++ic) {
        const float* inp = inb + ic*HW;
        const float* wp  = wb + ic*KK;
        #pragma unroll
        for (int ky = 0; ky < K; ++ky) {
            const int  y  = h + ky*DIL - PAD;
            const bool yv = (y >= 0) && (y < HH);
            const int  yc = yv ? y : 0;
            const float* row = inp + yc*WW;
            #pragma unroll
            for (int kx = 0; kx < K; ++kx) {
                const int  xx = x + kx*DIL - PAD;
                const bool v  = yv && (xx >= 0) && (xx < WW);
                const int  xc = (xx < 0) ? 0 : ((xx >= WW) ? (WW-1) : xx);
                float val = row[xc];
                val = v ? val : 0.f;
                const int t = ky*K + kx;
                #pragma unroll
                for (int o = 0; o < OCB; ++o)
                    acc[o] += wp[(size_t)o*CC*KK + t] * val;
            }
        }
    }

    if (x >= WW) return;
    #pragma unroll
    for (int o = 0; o < OCB; ++o)
        out[((size_t)b*COUT + oc0 + o)*HW + h*WW + x] = acc[o];
}

template<int K, int DIL, int PAD>
__global__ __launch_bounds__(64)
void deform_dw_full_kernel(const float* __restrict__ in, const float* __restrict__ off,
                           const float* __restrict__ dw, float* __restrict__ out) {
    constexpr int KK = K*K;
    const int idx = blockIdx.x*64 + threadIdx.x;
    const int x = idx % WW;
    const int h = (idx / WW) % HH;
    const int c = (idx / HW) % CC;
    const int b = idx / (CC*HW);

    const float* inp  = in  + ((size_t)b*CC + c)*HW;
    const float* offp = off + (size_t)b*(2*KK)*HW + h*WW + x;
    const float* dwp  = dw  + c*KK;

    float acc = 0.f;
    #pragma unroll 7
    for (int k = 0; k < KK; ++k) {
        const float dy = offp[(2*k  )*HW];
        const float dx = offp[(2*k+1)*HW];
        const float py = (float)(h + (k/K)*DIL - PAD) + dy;
        const float px = (float)(x + (k%K)*DIL - PAD) + dx;
        const float y0f = floorf(py), x0f = floorf(px);
        const float wy1 = py - y0f,  wx1 = px - x0f;
        const float wy0 = 1.f - wy1, wx0 = 1.f - wx1;
        const int y0 = (int)y0f, x0 = (int)x0f;

        const int y0c = min(max(y0,   0), HH-1);
        const int y1c = min(max(y0+1, 0), HH-1);
        const int x0c = min(max(x0,   0), WW-1);
        const int x1c = min(max(x0+1, 0), WW-1);
        const float my0 = (y0   >= 0 && y0   < HH) ? 1.f : 0.f;
        const float my1 = (y0+1 >= 0 && y0+1 < HH) ? 1.f : 0.f;
        const float mx0 = (x0   >= 0 && x0   < WW) ? 1.f : 0.f;
        const float mx1 = (x0+1 >= 0 && x0+1 < WW) ? 1.f : 0.f;

        const float v00 = inp[y0c*WW + x0c];
        const float v01 = inp[y0c*WW + x1c];
        const float v10 = inp[y1c*WW + x0c];
        const float v11 = inp[y1c*WW + x1c];

        const float gx0 = wx0*mx0, gx1 = wx1*mx1;
        const float s = (v00*gx0 + v01*gx1) * (wy0*my0)
                      + (v10*gx0 + v11*gx1) * (wy1*my1);
        acc += s * dwp[k];
    }
    out[idx] = acc;
}

__global__ __launch_bounds__(256)
void pw_mul_kernel(const float* __restrict__ x, const float* __restrict__ a2,
                   const float* __restrict__ pw, const float* __restrict__ pb,
                   float* __restrict__ out) {
    constexpr int HW4 = HW/4;
    const int t = blockIdx.x*256 + threadIdx.x;
    if (t >= BB*CC*HW4) return;
    const int sp4 = t % HW4;
    const int oc  = (t / HW4) % CC;
    const int b   = t / (CC*HW4);

    const float4* ap = (const float4*)(a2 + (size_t)b*CC*HW) + sp4;
    const float4* wp4 = (const float4*)(pw + oc*CC);
    const float pbv = pb[oc];
    float4 acc = make_float4(pbv, pbv, pbv, pbv);
    #pragma unroll 4
    for (int ic4 = 0; ic4 < CC/4; ++ic4) {
        const float4 w = wp4[ic4];
        float4 a0 = ap[(ic4*4+0)*HW4];
        float4 a1 = ap[(ic4*4+1)*HW4];
        float4 a2v = ap[(ic4*4+2)*HW4];
        float4 a3 = ap[(ic4*4+3)*HW4];
        acc.x += w.x*a0.x + w.y*a1.x + w.z*a2v.x + w.w*a3.x;
        acc.y += w.x*a0.y + w.y*a1.y + w.z*a2v.y + w.w*a3.y;
        acc.z += w.x*a0.z + w.y*a1.z + w.z*a2v.z + w.w*a3.z;
        acc.w += w.x*a0.w + w.y*a1.w + w.z*a2v.w + w.w*a3.w;
    }
    const float4 xv = ((const float4*)x)[t];
    float4 r;
    r.x = xv.x*acc.x; r.y = xv.y*acc.y; r.z = xv.z*acc.z; r.w = xv.w*acc.w;
    ((float4*)out)[t] = r;
}

extern "C" void kernel_launch(void* const* d_in, const int* in_sizes, int n_in,
                              void* d_out, int out_size, void* d_ws, size_t ws_size,
                              hipStream_t stream) {
    const float* x      = (const float*)d_in[0];
    const float* off_w1 = (const float*)d_in[1];
    const float* off_b1 = (const float*)d_in[2];
    const float* dw_w1  = (const float*)d_in[3];
    const float* off_w2 = (const float*)d_in[4];
    const float* off_b2 = (const float*)d_in[5];
    const float* dw_w2  = (const float*)d_in[6];
    const float* pw_w   = (const float*)d_in[7];
    const float* pw_b   = (const float*)d_in[8];
    float* out = (float*)d_out;

    const size_t nF    = (size_t)BB*CC*HW;
    const size_t attnB = nF*sizeof(float);                 // 3,211,264
    const size_t off2B = (size_t)BB*98*HW*sizeof(float);   // 4,917,248
    const size_t chB   = (size_t)BB*HW*64*sizeof(u16);     // 1,605,632
    char* ws = (char*)d_ws;

    const int n    = (int)nF;
    const int dbl  = n/64;
    const int pbl  = (n/4 + 255)/256;
    dim3 cblk(64,4);
    dim3 rgrd1(BB*(50/5), HH/4);
    dim3 rgrd2(BB*(98/7), HH/4);
    const int tgrid = BB*(HW/64);            // 196
    dim3 cgrd1(tgrid, 4);                    // conv1: NP=64  -> 4 n-tiles
    dim3 cgrd2(tgrid, 7);                    // conv2: NP=112 -> 7 n-tiles
    dim3 pgrd(tgrid, 4);                     // pw:    64 ch  -> 4 n-tiles
    const int dgrid = BB*HW/4;               // wave-per-pixel deform

    const size_t oOFF  = 0;
    const size_t oXT   = oOFF + off2B;
    const size_t oA1T  = oXT  + chB;
    const size_t oA2T  = oA1T + chB;
    const size_t oW1   = oA2T + chB;
    const size_t oW2   = oW1  + (size_t)R1*2;
    const size_t oPWT  = oW2  + (size_t)R2*2;
    const size_t oDW1  = oPWT + (size_t)R3*2;
    const size_t oDW2  = oDW1 + (size_t)R4*4;
    const size_t TOT   = oDW2 + (size_t)R5*4;

    if (ws_size >= TOT) {
        float* off_buf = (float*)(ws + oOFF);
        u16*   xT      = (u16*)(ws + oXT);
        u16*   a1T     = (u16*)(ws + oA1T);
        u16*   a2T     = (u16*)(ws + oA2T);
        u16*   w2t1    = (u16*)(ws + oW1);
        u16*   w2t2    = (u16*)(ws + oW2);
        u16*   pwT     = (u16*)(ws + oPWT);
        float* dwT1    = (float*)(ws + oDW1);
        float* dwT2    = (float*)(ws + oDW2);

        prep_all_kernel<<<(R1+R2+R3+R4+R5+255)/256, 256, 0, stream>>>(
            off_w1, off_w2, pw_w, dw_w1, dw_w2, w2t1, w2t2, pwT, dwT1, dwT2);
        transpose_bf16_kernel<<<tgrid, 256, 0, stream>>>(x, xT);

        conv_mfma_kernel<5,1,2,50,64><<<cgrd1, 256, 0, stream>>>(xT, w2t1, off_b1, off_buf);
        deform_cl_kernel<5,1,2><<<dgrid, 256, 0, stream>>>(xT, off_buf, dwT1, a1T);

        conv_mfma_kernel<7,3,9,98,112><<<cgrd2, 256, 0, stream>>>(a1T, w2t2, off_b2, off_buf);
        deform_cl_kernel<7,3,9><<<dgrid, 256, 0, stream>>>(a1T, off_buf, dwT2, a2T);

        pw_mfma_kernel<<<pgrd, 256, 0, stream>>>(a2T, pwT, pw_b, x, out);
    } else if (ws_size >= off2B + attnB) {
        float* off_buf = (float*)ws;
        float* attn1   = (float*)d_out;
        float* attn2   = (float*)(ws + off2B);
        off_conv_sg_kernel<5,1,2,50,5><<<rgrd1, cblk, 0, stream>>>(x, off_w1, off_b1, off_buf);
        deform_dw_full_kernel<5,1,2><<<dbl, 64, 0, stream>>>(x, off_buf, dw_w1, attn1);
        off_conv_sg_kernel<7,3,9,98,7><<<rgrd2, cblk, 0, stream>>>(attn1, off_w2, off_b2, off_buf);
        deform_dw_full_kernel<7,3,9><<<dbl, 64, 0, stream>>>(attn1, off_buf, dw_w2, attn2);
        pw_mul_kernel<<<pbl, 256, 0, stream>>>(x, attn2, pw_w, pw_b, out);
    } else {
        float* attn1 = (float*)d_out;
        float* attn2 = (float*)ws;
        float* off1  = (float*)ws;
        off_conv_sg_kernel<5,1,2,50,5><<<rgrd1, cblk, 0, stream>>>(x, off_w1, off_b1, off1);
        deform_dw_full_kernel<5,1,2><<<dbl, 64, 0, stream>>>(x, off1, dw_w1, attn1);
        float* off2 = (float*)(ws + attnB);
        off_conv_sg_kernel<7,3,9,98,7><<<rgrd2, cblk, 0, stream>>>(attn1, off_w2, off_b2, off2);
        deform_dw_full_kernel<7,3,9><<<dbl, 64, 0, stream>>>(attn1, off2, dw_w2, attn2);
        pw_mul_kernel<<<pbl, 256, 0, stream>>>(x, attn2, pw_w, pw_b, out);
    }
}